// Round 4
// baseline (7227.121 us; speedup 1.0000x reference)
//
#include <hip/hip_runtime.h>

// Equivariant graph attention — fp32. R4 = R3 algebra + register-budget fix:
//  - batch 4 edges/wave (not 8): accumulators+temps fit without spills
//  - persistent blocks (grid=512): stage 64KB LDS weights once per block
//  - hs 1KB/wave; output-linear weights from global (L1-hot)
// Algebra: sa = sqrt(expw)*rsqrt(z); z factors out of aggregation -> single
// pass per node, A[dst] resident as a 16-VGPR lane-owned fragment.

constexpr float INV3    = 0.57735026918962576f;  // 1/sqrt(3)
constexpr float INV_SQ8 = 0.35355339059327373f;  // 1/sqrt(8)   folded into w1 regs
constexpr float INV_HID = 0.125f;                // 1/sqrt(64)  folded into LDS w2
constexpr float INV_FAN = 0.015625f;             // 1/sqrt(4*32*32)
constexpr float INV_L   = 0.125f;                // 1/sqrt(64)

__device__ __forceinline__ float gelu_tanh(float x) {
  float u = 0.7978845608028654f * (x + 0.044715f * x * x * x);
  float e = __expf(2.0f * u);
  return x * (1.0f - 1.0f / (e + 1.0f));
}

// ---------------- CSR build ----------------
__global__ void k_zero(int* __restrict__ p, int n) {
  int i = blockIdx.x * 256 + threadIdx.x;
  if (i < n) p[i] = 0;
}

__global__ void k_hist(const int* __restrict__ dst, int* __restrict__ cnt, int E) {
  int e = blockIdx.x * 256 + threadIdx.x;
  if (e < E) atomicAdd(&cnt[dst[e]], 1);
}

__global__ __launch_bounds__(256) void k_scan(const int* __restrict__ cnt,
                                              int* __restrict__ rowptr, int N) {
  __shared__ int wsum[4];
  __shared__ int woff[4];
  __shared__ int carry;
  int t = threadIdx.x, wave = t >> 6, lane = t & 63;
  if (t == 0) { carry = 0; rowptr[0] = 0; }
  __syncthreads();
  for (int base = 0; base < N; base += 1024) {
    int i0 = base + t * 4;
    int c0 = (i0     < N) ? cnt[i0]     : 0;
    int c1 = (i0 + 1 < N) ? cnt[i0 + 1] : 0;
    int c2 = (i0 + 2 < N) ? cnt[i0 + 2] : 0;
    int c3 = (i0 + 3 < N) ? cnt[i0 + 3] : 0;
    int s0 = c0, s1 = s0 + c1, s2 = s1 + c2, s3 = s2 + c3;
    int inc = s3;
#pragma unroll
    for (int off = 1; off < 64; off <<= 1) {
      int y = __shfl_up(inc, off, 64);
      if (lane >= off) inc += y;
    }
    if (lane == 63) wsum[wave] = inc;
    __syncthreads();
    if (t == 0) {
      int r = 0;
      for (int w = 0; w < 4; w++) { woff[w] = r; r += wsum[w]; }
    }
    __syncthreads();
    int excl = inc - s3 + woff[wave] + carry;
    if (i0     < N) rowptr[i0 + 1] = excl + s0;
    if (i0 + 1 < N) rowptr[i0 + 2] = excl + s1;
    if (i0 + 2 < N) rowptr[i0 + 3] = excl + s2;
    if (i0 + 3 < N) rowptr[i0 + 4] = excl + s3;
    __syncthreads();
    if (t == 255) carry = excl + s3;
    __syncthreads();
  }
}

__global__ void k_fill(const int* __restrict__ dst, const int* __restrict__ rowptr,
                       int* __restrict__ cursor, int* __restrict__ csr, int E) {
  int e = blockIdx.x * 256 + threadIdx.x;
  if (e < E) {
    int d = dst[e];
    int s = atomicAdd(&cursor[d], 1);
    csr[rowptr[d] + s] = e;
  }
}

// ---------------- per-node A precompute ----------------
// Lane-owned layout: A[n][lane2][r], lane2=0..63, r=0..15.
//   lane2 = v    : r0..3 = A0[h=r][v]; r=4+3h+d = A2[h][v][d]
//   lane2 = 32+v : r0..3 = A1[h=r][v]; r=4+3h+d = A3[h][v][d]
__global__ __launch_bounds__(256) void k_nodeA(const float* __restrict__ node_f,
                                               const float* __restrict__ Wdot,
                                               float* __restrict__ A, int N) {
  __shared__ float Wd[16384];
  __shared__ float nfs[32 * 128];
  int t = threadIdx.x;
  for (int i = t; i < 16384; i += 256) Wd[i] = Wdot[i];
  int n0 = blockIdx.x * 32;
  int nEnd = min(32, N - n0);
  for (int i = t; i < nEnd * 128; i += 256) nfs[i] = node_f[n0 * 128 + i];
  __syncthreads();
  for (int nn = 0; nn < nEnd; ++nn) {
    const float* nf = &nfs[nn * 128];
    float* An = &A[(size_t)(n0 + nn) * 1024];
#pragma unroll
    for (int k = 0; k < 4; k++) {
      int o = t + k * 256;          // o = lane2*16 + r
      int lane2 = o >> 4, r = o & 15;
      int v = lane2 & 31;
      bool hi2 = lane2 >= 32;
      float acc = 0.f;
      if (r < 4) {
        const float* W = &Wd[(hi2 ? 4096 : 0) + r * 1024 + v];
#pragma unroll
        for (int u = 0; u < 32; u++) acc += W[u * 32] * nf[u];
      } else {
        int rr = r - 4;
        int h = rr / 3, d = rr - 3 * h;
        const float* W = &Wd[(hi2 ? 3 * 4096 : 2 * 4096) + h * 1024 + v];
#pragma unroll
        for (int u = 0; u < 32; u++) acc += W[u * 32] * nf[32 + 3 * u + d];
      }
      An[o] = acc;
    }
  }
}

// ---------------- fused persistent per-node pass ----------------
#define GR_BLOCKS 512

__global__ __launch_bounds__(256, 2) void k_graph(
    const int* __restrict__ csr, const int* __restrict__ rowptr,
    const int* __restrict__ esrc,
    const float* __restrict__ xattr, const float* __restrict__ eattr,
    const float* __restrict__ cutoff, const float* __restrict__ node_f,
    const float* __restrict__ wk1, const float* __restrict__ bk1,
    const float* __restrict__ wk2,
    const float* __restrict__ wv1, const float* __restrict__ bv1,
    const float* __restrict__ wv2,
    const float* __restrict__ Wls, const float* __restrict__ Wlv,
    const float* __restrict__ A,
    float* __restrict__ out, int N)
{
  __shared__ __align__(16) float4 w2k[16 * 128];  // 32 KiB  [q][j].[l%4], *INV_HID
  __shared__ __align__(16) float4 w2v[16 * 128];  // 32 KiB
  __shared__ __align__(16) float  hsb[4][256];    //  4 KiB  per-wave h / agg buffer

  int t = threadIdx.x, wave = t >> 6, lane = t & 63;
  for (int idx = t; idx < 8192; idx += 256) {
    int l = idx >> 7, j = idx & 127;
    ((float*)&w2k[(l >> 2) * 128 + j])[l & 3] = wk2[idx] * INV_HID;
    ((float*)&w2v[(l >> 2) * 128 + j])[l & 3] = wv2[idx] * INV_HID;
  }
  float w1kr[8], w1vr[8];
#pragma unroll
  for (int r = 0; r < 8; r++) {
    w1kr[r] = wk1[r * 64 + lane] * INV_SQ8;
    w1vr[r] = wv1[r * 64 + lane] * INV_SQ8;
  }
  float b1k = bk1[lane], b1v = bv1[lane];
  __syncthreads();   // only barrier

  int v = lane & 31;
  bool hi_ = lane >= 32;
  int hh = v >> 3;                  // head of this lane's channel
  float* hs = hsb[wave];
  const float4* xattr4 = (const float4*)xattr;
  const float4* eattr4 = (const float4*)eattr;

  // persistent: each wave strides over nodes
  for (int n = blockIdx.x * 4 + wave; n < N; n += GR_BLOCKS * 4) {
    // A fragment: the 16 values this lane needs, 4x float4 coalesced
    float Ar[16];
    {
      const float4* Ap = (const float4*)(A + (size_t)n * 1024 + lane * 16);
      float4 q0 = Ap[0], q1 = Ap[1], q2 = Ap[2], q3 = Ap[3];
      Ar[0] = q0.x;  Ar[1] = q0.y;  Ar[2] = q0.z;  Ar[3] = q0.w;
      Ar[4] = q1.x;  Ar[5] = q1.y;  Ar[6] = q1.z;  Ar[7] = q1.w;
      Ar[8] = q2.x;  Ar[9] = q2.y;  Ar[10] = q2.z; Ar[11] = q2.w;
      Ar[12] = q3.x; Ar[13] = q3.y; Ar[14] = q3.z; Ar[15] = q3.w;
    }
    int row0 = rowptr[n];
    int deg  = rowptr[n + 1] - row0;
    float accS = 0.f, ac0 = 0.f, ac1 = 0.f, ac2 = 0.f, zacc = 0.f;

    for (int sb = 0; sb < deg; sb += 4) {
      int eid[4]; float hv[4];
#pragma unroll
      for (int k = 0; k < 4; k++) {
        int s = sb + k;
        eid[k] = csr[row0 + (s < deg ? s : 0)];   // tail: dup edge, masked later
      }
      // layer 1, both MLPs (lane = hidden unit, 4 edges batched)
#pragma unroll
      for (int k = 0; k < 4; k++) {
        float4 xa = xattr4[(size_t)eid[k] * 2];
        float4 xb = xattr4[(size_t)eid[k] * 2 + 1];
        float ak = xa.x * w1kr[0] + xa.y * w1kr[1] + xa.z * w1kr[2] + xa.w * w1kr[3]
                 + xb.x * w1kr[4] + xb.y * w1kr[5] + xb.z * w1kr[6] + xb.w * w1kr[7];
        float av = xa.x * w1vr[0] + xa.y * w1vr[1] + xa.z * w1vr[2] + xa.w * w1vr[3]
                 + xb.x * w1vr[4] + xb.y * w1vr[5] + xb.z * w1vr[6] + xb.w * w1vr[7];
        hs[k * 64 + lane] = gelu_tanh(ak + b1k);
        hv[k] = gelu_tanh(av + b1v);
      }
      // layer 2, k-MLP: lane owns outputs j=lane, j=lane+64
      float a0k[4] = {0,0,0,0}, a1k[4] = {0,0,0,0};
#pragma unroll
      for (int q = 0; q < 16; ++q) {
        float4 wA = w2k[q * 128 + lane];
        float4 wB = w2k[q * 128 + 64 + lane];
#pragma unroll
        for (int k = 0; k < 4; k++) {
          float4 hq = *(const float4*)&hs[k * 64 + q * 4];
          a0k[k] += hq.x * wA.x + hq.y * wA.y + hq.z * wA.z + hq.w * wA.w;
          a1k[k] += hq.x * wB.x + hq.y * wB.y + hq.z * wB.z + hq.w * wB.w;
        }
      }
      // swap h buffer to v-MLP (same-wave LDS, in-order, no barrier)
#pragma unroll
      for (int k = 0; k < 4; k++) hs[k * 64 + lane] = hv[k];
      float a0v[4] = {0,0,0,0}, a1v[4] = {0,0,0,0};
#pragma unroll
      for (int q = 0; q < 16; ++q) {
        float4 wA = w2v[q * 128 + lane];
        float4 wB = w2v[q * 128 + 64 + lane];
#pragma unroll
        for (int k = 0; k < 4; k++) {
          float4 hq = *(const float4*)&hs[k * 64 + q * 4];
          a0v[k] += hq.x * wA.x + hq.y * wA.y + hq.z * wA.z + hq.w * wA.w;
          a1v[k] += hq.x * wB.x + hq.y * wB.y + hq.z * wB.z + hq.w * wB.w;
        }
      }
      // per-edge epilogue: logit -> expw -> z & sqrt(expw)*v accumulation
#pragma unroll
      for (int k = 0; k < 4; k++) {
        int s = sb + k, e = eid[k];
        float4 ya = eattr4[e];
        float cut = cutoff[e];
        const float* nf = node_f + (size_t)esrc[e] * 128;
        float nf0 = nf[hi_ ? 32 + 3 * v : v];
        float nf1 = nf[hi_ ? 33 + 3 * v : v];
        float nf2 = nf[hi_ ? 34 + 3 * v : v];
        float dotv = nf0 * ya.y + nf1 * ya.z + nf2 * ya.w;
        // lo: k0 = w0*sxs*ys, kv0-term: INV3*w2*sxs*(A2[h,v,:].yv)
        // hi: k1 = w0*(sxv.yv)*INV3, kv1-term: INV3*w3*ys*(A3[h,v,:].sxv)
        float kscal = hi_ ? (a0k[k] * dotv * INV3) : (a0k[k] * nf0 * ya.x);
        float cf = INV3 * a1k[k] * (hi_ ? ya.x : nf0);
        float m0 = hi_ ? nf0 : ya.y, m1 = hi_ ? nf1 : ya.z, m2 = hi_ ? nf2 : ya.w;
        float p0 = Ar[0] * kscal + cf * (Ar[4]  * m0 + Ar[5]  * m1 + Ar[6]  * m2);
        float p1 = Ar[1] * kscal + cf * (Ar[7]  * m0 + Ar[8]  * m1 + Ar[9]  * m2);
        float p2 = Ar[2] * kscal + cf * (Ar[10] * m0 + Ar[11] * m1 + Ar[12] * m2);
        float p3 = Ar[3] * kscal + cf * (Ar[13] * m0 + Ar[14] * m1 + Ar[15] * m2);
#pragma unroll
        for (int off = 32; off; off >>= 1) {
          p0 += __shfl_xor(p0, off, 64);
          p1 += __shfl_xor(p1, off, 64);
          p2 += __shfl_xor(p2, off, 64);
          p3 += __shfl_xor(p3, off, 64);
        }
        float ph = (hh & 2) ? ((hh & 1) ? p3 : p2) : ((hh & 1) ? p1 : p0);
        float ew = (s < deg) ? cut * __expf(ph * INV_FAN) : 0.f;
        zacc += ew;                 // lane's zacc accumulates z of its head hh
        float sq = sqrtf(ew);       // sa = sqrt(ew)*rsqrt(z), rz applied later
        float sterm = hi_ ? dotv * INV3 : nf0 * ya.x;
        accS += a0v[k] * sterm * sq;
        float coef = a1v[k] * sq * (hi_ ? ya.x : nf0);
        ac0 += coef * m0; ac1 += coef * m1; ac2 += coef * m2;
      }
    }

    float rz = rsqrtf(zacc == 0.f ? 1.f : zacc);   // z==0 -> 1 guard
    accS *= rz; ac0 *= rz; ac1 *= rz; ac2 *= rz;

    // stage agg channels in hs (wave-local), then fused output linear
    {
      int chS = hi_ ? 32 + v : v;
      int chV = (hi_ ? 160 : 64) + 3 * v;
      hs[chS] = accS;
      hs[chV] = ac0; hs[chV + 1] = ac1; hs[chV + 2] = ac2;
    }
#pragma unroll
    for (int jj = 0; jj < 2; ++jj) {
      int j = 2 * lane + jj;
      float o = 0.f;
      if (j < 32) {
#pragma unroll
        for (int u = 0; u < 64; u++) o += hs[u] * Wls[u * 32 + j];
      } else {
        int i2 = j - 32, w2i = i2 / 3, d2 = i2 - 3 * w2i;
#pragma unroll
        for (int u = 0; u < 64; u++) o += hs[64 + u * 3 + d2] * Wlv[u * 32 + w2i];
      }
      out[(size_t)n * 128 + j] = o * INV_L;
    }
  }
}

// ---------------- host launcher ----------------
extern "C" void kernel_launch(void* const* d_in, const int* in_sizes, int n_in,
                              void* d_out, int out_size, void* d_ws, size_t ws_size,
                              hipStream_t stream) {
  const int*   esrc   = (const int*)d_in[0];
  const int*   edst   = (const int*)d_in[1];
  const float* xattr  = (const float*)d_in[2];
  const float* eattr  = (const float*)d_in[3];
  const float* cutoff = (const float*)d_in[4];
  const float* node_f = (const float*)d_in[5];
  const float* wk1    = (const float*)d_in[6];
  const float* bk1    = (const float*)d_in[7];
  const float* wk2    = (const float*)d_in[8];
  const float* wv1    = (const float*)d_in[9];
  const float* bv1    = (const float*)d_in[10];
  const float* wv2    = (const float*)d_in[11];
  const float* Wdot   = (const float*)d_in[12];
  const float* Wls    = (const float*)d_in[13];
  const float* Wlv    = (const float*)d_in[14];
  float* out = (float*)d_out;

  int E = in_sizes[0];
  int N = in_sizes[5] / 128;

  // workspace (~42.5 MB): A | counts | cursor | rowptr | csr
  float* A    = (float*)d_ws;                  // N*1024 f32
  int* counts = (int*)(A + (size_t)N * 1024);  // N
  int* cursor = counts + N;                    // N
  int* rowptr = cursor + N;                    // N+1
  int* csr    = rowptr + (N + 1);              // E

  k_zero<<<(2 * N + 255) / 256, 256, 0, stream>>>(counts, 2 * N);
  k_hist<<<(E + 255) / 256, 256, 0, stream>>>(edst, counts, E);
  k_scan<<<1, 256, 0, stream>>>(counts, rowptr, N);
  k_fill<<<(E + 255) / 256, 256, 0, stream>>>(edst, rowptr, cursor, csr, E);
  k_nodeA<<<(N + 31) / 32, 256, 0, stream>>>(node_f, Wdot, A, N);
  k_graph<<<GR_BLOCKS, 256, 0, stream>>>(csr, rowptr, esrc, xattr, eattr, cutoff,
                                         node_f, wk1, bk1, wk2, wv1, bv1, wv2,
                                         Wls, Wlv, A, out, N);
}

// Round 5
// 2169.076 us; speedup vs baseline: 3.3319x; 3.3319x over previous
//
#include <hip/hip_runtime.h>

// Equivariant graph attention — fp32. R5: R3's per-node algebra, SPLIT into
// two persistent kernels (k-path / v-path) so each stays under the spill
// threshold. Cross-round evidence: R2/R3/R4 all spilled (WRITE_SIZE GBs vs
// 5 MB legit); R1's split kernels never spilled. Live state per kernel here:
// Ar[16]+w1[9]+acc[8]+eid[4]+misc ≈ 80 VGPR -> no spill expected.
//   k_edge1: per-node wave: k-MLP(4 edges batched) -> logit vs lane-owned A
//            fragment -> expw store (E x 4).
//   k_edge2: per-node wave: z from expw, v-MLP -> sqrt(expw)*v accumulate,
//            rsqrt(z) at end, fused output linear.

constexpr float INV3    = 0.57735026918962576f;  // 1/sqrt(3)
constexpr float INV_SQ8 = 0.35355339059327373f;  // 1/sqrt(8)   folded into w1 regs
constexpr float INV_HID = 0.125f;                // 1/sqrt(64)  folded into LDS w2
constexpr float INV_FAN = 0.015625f;             // 1/sqrt(4*32*32)
constexpr float INV_L   = 0.125f;                // 1/sqrt(64)
#define GR_BLOCKS 1024

__device__ __forceinline__ float gelu_tanh(float x) {
  float u = 0.7978845608028654f * (x + 0.044715f * x * x * x);
  float e = __expf(2.0f * u);
  return x * (1.0f - 1.0f / (e + 1.0f));
}

// ---------------- CSR build ----------------
__global__ void k_zero(int* __restrict__ p, int n) {
  int i = blockIdx.x * 256 + threadIdx.x;
  if (i < n) p[i] = 0;
}

__global__ void k_hist(const int* __restrict__ dst, int* __restrict__ cnt, int E) {
  int e = blockIdx.x * 256 + threadIdx.x;
  if (e < E) atomicAdd(&cnt[dst[e]], 1);
}

__global__ __launch_bounds__(256) void k_scan(const int* __restrict__ cnt,
                                              int* __restrict__ rowptr, int N) {
  __shared__ int wsum[4];
  __shared__ int woff[4];
  __shared__ int carry;
  int t = threadIdx.x, wave = t >> 6, lane = t & 63;
  if (t == 0) { carry = 0; rowptr[0] = 0; }
  __syncthreads();
  for (int base = 0; base < N; base += 1024) {
    int i0 = base + t * 4;
    int c0 = (i0     < N) ? cnt[i0]     : 0;
    int c1 = (i0 + 1 < N) ? cnt[i0 + 1] : 0;
    int c2 = (i0 + 2 < N) ? cnt[i0 + 2] : 0;
    int c3 = (i0 + 3 < N) ? cnt[i0 + 3] : 0;
    int s0 = c0, s1 = s0 + c1, s2 = s1 + c2, s3 = s2 + c3;
    int inc = s3;
#pragma unroll
    for (int off = 1; off < 64; off <<= 1) {
      int y = __shfl_up(inc, off, 64);
      if (lane >= off) inc += y;
    }
    if (lane == 63) wsum[wave] = inc;
    __syncthreads();
    if (t == 0) {
      int r = 0;
      for (int w = 0; w < 4; w++) { woff[w] = r; r += wsum[w]; }
    }
    __syncthreads();
    int excl = inc - s3 + woff[wave] + carry;
    if (i0     < N) rowptr[i0 + 1] = excl + s0;
    if (i0 + 1 < N) rowptr[i0 + 2] = excl + s1;
    if (i0 + 2 < N) rowptr[i0 + 3] = excl + s2;
    if (i0 + 3 < N) rowptr[i0 + 4] = excl + s3;
    __syncthreads();
    if (t == 255) carry = excl + s3;
    __syncthreads();
  }
}

__global__ void k_fill(const int* __restrict__ dst, const int* __restrict__ rowptr,
                       int* __restrict__ cursor, int* __restrict__ csr, int E) {
  int e = blockIdx.x * 256 + threadIdx.x;
  if (e < E) {
    int d = dst[e];
    int s = atomicAdd(&cursor[d], 1);
    csr[rowptr[d] + s] = e;
  }
}

// ---------------- per-node A precompute ----------------
// Lane-owned layout: A[n][lane2][r], lane2=0..63, r=0..15.
//   lane2 = v    : r0..3 = A0[h=r][v]; r=4+3h+d = A2[h][v][d]
//   lane2 = 32+v : r0..3 = A1[h=r][v]; r=4+3h+d = A3[h][v][d]
__global__ __launch_bounds__(256) void k_nodeA(const float* __restrict__ node_f,
                                               const float* __restrict__ Wdot,
                                               float* __restrict__ A, int N) {
  __shared__ float Wd[16384];
  __shared__ float nfs[32 * 128];
  int t = threadIdx.x;
  for (int i = t; i < 16384; i += 256) Wd[i] = Wdot[i];
  int n0 = blockIdx.x * 32;
  int nEnd = min(32, N - n0);
  for (int i = t; i < nEnd * 128; i += 256) nfs[i] = node_f[n0 * 128 + i];
  __syncthreads();
  for (int nn = 0; nn < nEnd; ++nn) {
    const float* nf = &nfs[nn * 128];
    float* An = &A[(size_t)(n0 + nn) * 1024];
#pragma unroll
    for (int k = 0; k < 4; k++) {
      int o = t + k * 256;          // o = lane2*16 + r
      int lane2 = o >> 4, r = o & 15;
      int v = lane2 & 31;
      bool hi2 = lane2 >= 32;
      float acc = 0.f;
      if (r < 4) {
        const float* W = &Wd[(hi2 ? 4096 : 0) + r * 1024 + v];
#pragma unroll
        for (int u = 0; u < 32; u++) acc += W[u * 32] * nf[u];
      } else {
        int rr = r - 4;
        int h = rr / 3, d = rr - 3 * h;
        const float* W = &Wd[(hi2 ? 3 * 4096 : 2 * 4096) + h * 1024 + v];
#pragma unroll
        for (int u = 0; u < 32; u++) acc += W[u * 32] * nf[32 + 3 * u + d];
      }
      An[o] = acc;
    }
  }
}

// ---------------- pass 1: k-MLP + logits -> expw ----------------
__global__ __launch_bounds__(256) void k_edge1(
    const int* __restrict__ csr, const int* __restrict__ rowptr,
    const int* __restrict__ esrc,
    const float* __restrict__ xattr, const float* __restrict__ eattr,
    const float* __restrict__ cutoff, const float* __restrict__ node_f,
    const float* __restrict__ wk1, const float* __restrict__ bk1,
    const float* __restrict__ wk2,
    const float* __restrict__ A,
    float* __restrict__ expw, int N)
{
  __shared__ __align__(16) float4 w2k[16 * 128];  // 32 KiB, [q][j].[l%4], *INV_HID
  __shared__ __align__(16) float  hsb[4][256];    //  4 KiB, per-wave h buffer

  int t = threadIdx.x, wave = t >> 6, lane = t & 63;
  for (int idx = t; idx < 8192; idx += 256) {
    int l = idx >> 7, j = idx & 127;
    ((float*)&w2k[(l >> 2) * 128 + j])[l & 3] = wk2[idx] * INV_HID;
  }
  float w1r[8];
#pragma unroll
  for (int r = 0; r < 8; r++) w1r[r] = wk1[r * 64 + lane] * INV_SQ8;
  float b1r = bk1[lane];
  __syncthreads();   // only barrier

  int v = lane & 31;
  bool hi_ = lane >= 32;
  float* hs = hsb[wave];
  const float4* xattr4 = (const float4*)xattr;
  const float4* eattr4 = (const float4*)eattr;

  for (int n = blockIdx.x * 4 + wave; n < N; n += GR_BLOCKS * 4) {
    float Ar[16];
    {
      const float4* Ap = (const float4*)(A + (size_t)n * 1024 + lane * 16);
      float4 q0 = Ap[0], q1 = Ap[1], q2 = Ap[2], q3 = Ap[3];
      Ar[0] = q0.x;  Ar[1] = q0.y;  Ar[2] = q0.z;  Ar[3] = q0.w;
      Ar[4] = q1.x;  Ar[5] = q1.y;  Ar[6] = q1.z;  Ar[7] = q1.w;
      Ar[8] = q2.x;  Ar[9] = q2.y;  Ar[10] = q2.z; Ar[11] = q2.w;
      Ar[12] = q3.x; Ar[13] = q3.y; Ar[14] = q3.z; Ar[15] = q3.w;
    }
    int row0 = rowptr[n];
    int deg  = rowptr[n + 1] - row0;

    for (int sb = 0; sb < deg; sb += 4) {
      int eid[4];
#pragma unroll
      for (int k = 0; k < 4; k++) {
        int s = sb + k;
        eid[k] = csr[row0 + (s < deg ? s : 0)];
      }
#pragma unroll
      for (int k = 0; k < 4; k++) {
        float4 xa = xattr4[(size_t)eid[k] * 2];
        float4 xb = xattr4[(size_t)eid[k] * 2 + 1];
        float ak = xa.x * w1r[0] + xa.y * w1r[1] + xa.z * w1r[2] + xa.w * w1r[3]
                 + xb.x * w1r[4] + xb.y * w1r[5] + xb.z * w1r[6] + xb.w * w1r[7];
        hs[k * 64 + lane] = gelu_tanh(ak + b1r);
      }
      float a0[4] = {0, 0, 0, 0}, a1[4] = {0, 0, 0, 0};
#pragma unroll
      for (int q = 0; q < 16; ++q) {
        float4 wA = w2k[q * 128 + lane];
        float4 wB = w2k[q * 128 + 64 + lane];
#pragma unroll
        for (int k = 0; k < 4; k++) {
          float4 hq = *(const float4*)&hs[k * 64 + q * 4];
          a0[k] += hq.x * wA.x + hq.y * wA.y + hq.z * wA.z + hq.w * wA.w;
          a1[k] += hq.x * wB.x + hq.y * wB.y + hq.z * wB.z + hq.w * wB.w;
        }
      }
#pragma unroll
      for (int k = 0; k < 4; k++) {
        int s = sb + k, e = eid[k];
        float4 ya = eattr4[e];
        float cut = cutoff[e];
        const float* nf = node_f + (size_t)esrc[e] * 128;
        float nf0 = nf[hi_ ? 32 + 3 * v : v];
        float nf1 = nf[hi_ ? 33 + 3 * v : v];
        float nf2 = nf[hi_ ? 34 + 3 * v : v];
        float dotv = nf0 * ya.y + nf1 * ya.z + nf2 * ya.w;
        float kscal = hi_ ? (a0[k] * dotv * INV3) : (a0[k] * nf0 * ya.x);
        float cf = INV3 * a1[k] * (hi_ ? ya.x : nf0);
        float m0 = hi_ ? nf0 : ya.y, m1 = hi_ ? nf1 : ya.z, m2 = hi_ ? nf2 : ya.w;
        float p0 = Ar[0] * kscal + cf * (Ar[4]  * m0 + Ar[5]  * m1 + Ar[6]  * m2);
        float p1 = Ar[1] * kscal + cf * (Ar[7]  * m0 + Ar[8]  * m1 + Ar[9]  * m2);
        float p2 = Ar[2] * kscal + cf * (Ar[10] * m0 + Ar[11] * m1 + Ar[12] * m2);
        float p3 = Ar[3] * kscal + cf * (Ar[13] * m0 + Ar[14] * m1 + Ar[15] * m2);
#pragma unroll
        for (int off = 32; off; off >>= 1) {
          p0 += __shfl_xor(p0, off, 64);
          p1 += __shfl_xor(p1, off, 64);
          p2 += __shfl_xor(p2, off, 64);
          p3 += __shfl_xor(p3, off, 64);
        }
        // lanes 0..3 write heads 0..3
        float ph = (lane & 2) ? ((lane & 1) ? p3 : p2) : ((lane & 1) ? p1 : p0);
        if (lane < 4 && s < deg)
          expw[(size_t)(row0 + s) * 4 + lane] = cut * __expf(ph * INV_FAN);
      }
    }
  }
}

// ---------------- pass 2: z, v-MLP, aggregation, output linear ----------------
__global__ __launch_bounds__(256) void k_edge2(
    const int* __restrict__ csr, const int* __restrict__ rowptr,
    const int* __restrict__ esrc,
    const float* __restrict__ xattr, const float* __restrict__ eattr,
    const float* __restrict__ node_f,
    const float* __restrict__ wv1, const float* __restrict__ bv1,
    const float* __restrict__ wv2,
    const float* __restrict__ Wls, const float* __restrict__ Wlv,
    const float* __restrict__ expw,
    float* __restrict__ out, int N)
{
  __shared__ __align__(16) float4 w2v[16 * 128];  // 32 KiB
  __shared__ __align__(16) float  hsb[4][256];    //  4 KiB

  int t = threadIdx.x, wave = t >> 6, lane = t & 63;
  for (int idx = t; idx < 8192; idx += 256) {
    int l = idx >> 7, j = idx & 127;
    ((float*)&w2v[(l >> 2) * 128 + j])[l & 3] = wv2[idx] * INV_HID;
  }
  float w1r[8];
#pragma unroll
  for (int r = 0; r < 8; r++) w1r[r] = wv1[r * 64 + lane] * INV_SQ8;
  float b1r = bv1[lane];
  __syncthreads();   // only barrier

  int v = lane & 31;
  bool hi_ = lane >= 32;
  int hh = v >> 3;
  float* hs = hsb[wave];
  const float4* xattr4 = (const float4*)xattr;
  const float4* eattr4 = (const float4*)eattr;

  for (int n = blockIdx.x * 4 + wave; n < N; n += GR_BLOCKS * 4) {
    int row0 = rowptr[n];
    int deg  = rowptr[n + 1] - row0;

    // z per head (lane hz=lane&3 accumulates head hz over slots lane>>2 stride 16)
    float pz = 0.f;
    {
      int hz = lane & 3;
      for (int s = lane >> 2; s < deg; s += 16)
        pz += expw[(size_t)(row0 + s) * 4 + hz];
#pragma unroll
      for (int off = 4; off < 64; off <<= 1) pz += __shfl_xor(pz, off, 64);
    }
    float zf = __shfl(pz, hh, 64);
    float rz = rsqrtf(zf == 0.f ? 1.f : zf);

    float accS = 0.f, ac0 = 0.f, ac1 = 0.f, ac2 = 0.f;
    for (int sb = 0; sb < deg; sb += 4) {
      int eid[4];
#pragma unroll
      for (int k = 0; k < 4; k++) {
        int s = sb + k;
        eid[k] = csr[row0 + (s < deg ? s : 0)];
      }
#pragma unroll
      for (int k = 0; k < 4; k++) {
        float4 xa = xattr4[(size_t)eid[k] * 2];
        float4 xb = xattr4[(size_t)eid[k] * 2 + 1];
        float av = xa.x * w1r[0] + xa.y * w1r[1] + xa.z * w1r[2] + xa.w * w1r[3]
                 + xb.x * w1r[4] + xb.y * w1r[5] + xb.z * w1r[6] + xb.w * w1r[7];
        hs[k * 64 + lane] = gelu_tanh(av + b1r);
      }
      float a0[4] = {0, 0, 0, 0}, a1[4] = {0, 0, 0, 0};
#pragma unroll
      for (int q = 0; q < 16; ++q) {
        float4 wA = w2v[q * 128 + lane];
        float4 wB = w2v[q * 128 + 64 + lane];
#pragma unroll
        for (int k = 0; k < 4; k++) {
          float4 hq = *(const float4*)&hs[k * 64 + q * 4];
          a0[k] += hq.x * wA.x + hq.y * wA.y + hq.z * wA.z + hq.w * wA.w;
          a1[k] += hq.x * wB.x + hq.y * wB.y + hq.z * wB.z + hq.w * wB.w;
        }
      }
#pragma unroll
      for (int k = 0; k < 4; k++) {
        int s = sb + k, e = eid[k];
        float4 ya = eattr4[e];
        const float* nf = node_f + (size_t)esrc[e] * 128;
        float nf0 = nf[hi_ ? 32 + 3 * v : v];
        float nf1 = nf[hi_ ? 33 + 3 * v : v];
        float nf2 = nf[hi_ ? 34 + 3 * v : v];
        float ew = (s < deg) ? expw[(size_t)(row0 + s) * 4 + hh] : 0.f;
        float sq = sqrtf(ew);     // sa = sqrt(ew)*rsqrt(z); rz applied at end
        float dotv = nf0 * ya.y + nf1 * ya.z + nf2 * ya.w;
        float sterm = hi_ ? dotv * INV3 : nf0 * ya.x;
        accS += a0[k] * sterm * sq;
        float coef = a1[k] * sq * (hi_ ? ya.x : nf0);
        float m0 = hi_ ? nf0 : ya.y, m1 = hi_ ? nf1 : ya.z, m2 = hi_ ? nf2 : ya.w;
        ac0 += coef * m0; ac1 += coef * m1; ac2 += coef * m2;
      }
    }
    accS *= rz; ac0 *= rz; ac1 *= rz; ac2 *= rz;

    // stage agg channels (wave-local), fused output linear
    {
      int chS = hi_ ? 32 + v : v;
      int chV = (hi_ ? 160 : 64) + 3 * v;
      hs[chS] = accS;
      hs[chV] = ac0; hs[chV + 1] = ac1; hs[chV + 2] = ac2;
    }
#pragma unroll
    for (int jj = 0; jj < 2; ++jj) {
      int j = 2 * lane + jj;
      float o = 0.f;
      if (j < 32) {
#pragma unroll
        for (int u = 0; u < 64; u++) o += hs[u] * Wls[u * 32 + j];
      } else {
        int i2 = j - 32, w2i = i2 / 3, d2 = i2 - 3 * w2i;
#pragma unroll
        for (int u = 0; u < 64; u++) o += hs[64 + u * 3 + d2] * Wlv[u * 32 + w2i];
      }
      out[(size_t)n * 128 + j] = o * INV_L;
    }
  }
}

// ---------------- host launcher ----------------
extern "C" void kernel_launch(void* const* d_in, const int* in_sizes, int n_in,
                              void* d_out, int out_size, void* d_ws, size_t ws_size,
                              hipStream_t stream) {
  const int*   esrc   = (const int*)d_in[0];
  const int*   edst   = (const int*)d_in[1];
  const float* xattr  = (const float*)d_in[2];
  const float* eattr  = (const float*)d_in[3];
  const float* cutoff = (const float*)d_in[4];
  const float* node_f = (const float*)d_in[5];
  const float* wk1    = (const float*)d_in[6];
  const float* bk1    = (const float*)d_in[7];
  const float* wk2    = (const float*)d_in[8];
  const float* wv1    = (const float*)d_in[9];
  const float* bv1    = (const float*)d_in[10];
  const float* wv2    = (const float*)d_in[11];
  const float* Wdot   = (const float*)d_in[12];
  const float* Wls    = (const float*)d_in[13];
  const float* Wlv    = (const float*)d_in[14];
  float* out = (float*)d_out;

  int E = in_sizes[0];
  int N = in_sizes[5] / 128;

  // workspace (~48 MB): A | expw | counts | cursor | rowptr | csr
  float* A     = (float*)d_ws;                  // N*1024 f32
  float* expw  = A + (size_t)N * 1024;          // E*4 f32
  int* counts  = (int*)(expw + (size_t)E * 4);  // N
  int* cursor  = counts + N;                    // N
  int* rowptr  = cursor + N;                    // N+1
  int* csr     = rowptr + (N + 1);              // E

  k_zero<<<(2 * N + 255) / 256, 256, 0, stream>>>(counts, 2 * N);
  k_hist<<<(E + 255) / 256, 256, 0, stream>>>(edst, counts, E);
  k_scan<<<1, 256, 0, stream>>>(counts, rowptr, N);
  k_fill<<<(E + 255) / 256, 256, 0, stream>>>(edst, rowptr, cursor, csr, E);
  k_nodeA<<<(N + 31) / 32, 256, 0, stream>>>(node_f, Wdot, A, N);
  k_edge1<<<GR_BLOCKS, 256, 0, stream>>>(csr, rowptr, esrc, xattr, eattr, cutoff,
                                         node_f, wk1, bk1, wk2, A, expw, N);
  k_edge2<<<GR_BLOCKS, 256, 0, stream>>>(csr, rowptr, esrc, xattr, eattr, node_f,
                                         wv1, bv1, wv2, Wls, Wlv, expw, out, N);
}